// Round 6
// baseline (187.244 us; speedup 1.0000x reference)
//
#include <hip/hip_runtime.h>
#include <math.h>

typedef unsigned short ushort_t;
typedef _Float16 f16_t;
typedef __attribute__((ext_vector_type(8))) _Float16 f16x8;
typedef __attribute__((ext_vector_type(4))) float f32x4;

#define NTOK 131072
#define MT   128      // tokens per block
#define TPB  256      // 4 waves; each wave owns 32 tokens end-to-end; ZERO barriers
#define RPAD 76       // relay row pad (fp16 elems)

// ws layout (f16 elems)
#define OFF_KEY 0
#define OFF_VAL 4096      // contiguous after KEY
#define OFF_T   8192      // 8 matrices of 4096 (p=0..6 T_W, p=7 = T_b)
#define OFF_D1  40960
#define OFF_D2  45056     // [32][64]
#define OFF_D3  47104     // [64][32]
#define WTOT    49152     // 96 KB fp16 total -> L2-resident

__device__ __forceinline__ f32x4 mfma1(f16x8 a, f16x8 b, f32x4 c) {
    return __builtin_amdgcn_mfma_f32_16x16x32_f16(a, b, c, 0, 0, 0);
}

struct Bfrag { f16x8 h0, h1; };
__device__ __forceinline__ Bfrag loadB(const f16_t* __restrict__ b, int off) {
    Bfrag r;
    r.h0 = *(const f16x8*)(b + off);
    r.h1 = *(const f16x8*)(b + off + 32);
    return r;
}

// K=64 GEMM, single row-tile
template<int NC>
__device__ __forceinline__ void gemm1rt(const f16_t* __restrict__ bw,
                                        int l15, int quad,
                                        const f16x8 ah[2], f32x4 acc[NC])
{
#pragma unroll
    for (int c = 0; c < NC; ++c) {
        Bfrag b = loadB(bw, (16 * c + l15) * 64 + quad * 8);
        f32x4 a = acc[c];
        a = mfma1(ah[0], b.h0, a);
        a = mfma1(ah[1], b.h1, a);
        acc[c] = a;
    }
}
// K=64 GEMM, B shared across both row-tiles
template<int NC>
__device__ __forceinline__ void gemm2rt(const f16_t* __restrict__ bw,
                                        int l15, int quad,
                                        const f16x8 ah[2][2], f32x4 acc[2][NC])
{
#pragma unroll
    for (int c = 0; c < NC; ++c) {
        Bfrag b = loadB(bw, (16 * c + l15) * 64 + quad * 8);
#pragma unroll
        for (int rt = 0; rt < 2; ++rt) {
            f32x4 a = acc[rt][c];
            a = mfma1(ah[rt][0], b.h0, a);
            a = mfma1(ah[rt][1], b.h1, a);
            acc[rt][c] = a;
        }
    }
}

// ---------------- prep: transpose all weights into ws as fp16 --------------
__global__ __launch_bounds__(256)
void prep_w(const float* __restrict__ keyW, const float* __restrict__ valW,
            const float* __restrict__ TW,   const float* __restrict__ TB,
            const float* __restrict__ d1W,  const float* __restrict__ d2W,
            const float* __restrict__ d3W,  f16_t* __restrict__ wsf)
{
    int idx = blockIdx.x * 256 + threadIdx.x;
    if (idx >= WTOT) return;
    float src;
    if (idx < OFF_VAL) {
        int r = idx - OFF_KEY, n = r >> 6, j = r & 63;
        src = keyW[j * 64 + n];
    } else if (idx < OFF_T) {
        int r = idx - OFF_VAL, n = r >> 6, j = r & 63;
        src = valW[j * 64 + n];
    } else if (idx < OFF_D1) {
        int r = idx - OFF_T, p = r >> 12, q = r & 4095;
        src = (p < 7) ? TW[p * 4096 + q] : TB[q];
    } else if (idx < OFF_D2) {
        int r = idx - OFF_D1, n = r >> 6, j = r & 63;
        src = d1W[j * 64 + n];
    } else if (idx < OFF_D3) {
        int r = idx - OFF_D2, n = r >> 6, j = r & 63;
        src = d2W[j * 32 + n];
    } else {
        int r = idx - OFF_D3, n = r >> 5, j = r & 31;
        src = d3W[j * 64 + n];
    }
    wsf[idx] = (f16_t)src;
}

// ---------------- main fused kernel: 4 waves, zero barriers ----------------
__global__ __launch_bounds__(TPB, 4)
void fused_mfma(const float* __restrict__ kv_in, const float* __restrict__ q_in,
                const float* __restrict__ keyB,  const float* __restrict__ valB,
                const float* __restrict__ d1B,   const float* __restrict__ d2B,
                const float* __restrict__ d3B,   const float* __restrict__ scale_p,
                const f16_t* __restrict__ wsf,   float* __restrict__ out)
{
    // Rly: fp16 staging of kv, later x/h relays. All accesses wave-private in
    // row space -> no barriers. Obuf: fp32 epilogue re-layout so HBM stores are
    // lane-contiguous float4 (full lines; kills the R5 RMW write storm).
    __shared__ __align__(16) f16_t Rly[MT][RPAD];   // 19456 B
    __shared__ __align__(16) float Qs[8][MT];       // 4096 B
    __shared__ __align__(16) float Obuf[4][16][66]; // 16896 B  -> 40448 B total, 4 blk/CU

    const int tid  = threadIdx.x;
    const int wv   = tid >> 6, lane = tid & 63;
    const int quad = lane >> 4, l15 = lane & 15;
    const int RB   = wv * 32;
    const long t0  = (long)blockIdx.x * MT;

    // ---- coalesced kv staging -> fp16 in LDS (wave-private rows) ----
    {
        const int r = RB + (lane >> 1), half = lane & 1;
        const float4* p4 = (const float4*)(kv_in + (t0 + r) * 64 + half * 32);
        f16_t* dst = &Rly[r][half * 32];
#pragma unroll
        for (int b = 0; b < 4; ++b) {
            float4 f0 = p4[2 * b], f1 = p4[2 * b + 1];
            f16x8 h;
            h[0] = (f16_t)f0.x; h[1] = (f16_t)f0.y; h[2] = (f16_t)f0.z; h[3] = (f16_t)f0.w;
            h[4] = (f16_t)f1.x; h[5] = (f16_t)f1.y; h[6] = (f16_t)f1.z; h[7] = (f16_t)f1.w;
            *(f16x8*)(dst + 8 * b) = h;
        }
    }
    // ---- q' -> Qs (wave-private cols) ----
    if (lane < 32) {
        const float* qp = q_in + (t0 + RB + lane) * 7;
#pragma unroll
        for (int p = 0; p < 7; ++p) Qs[p][RB + lane] = qp[p];
        Qs[7][RB + lane] = 1.0f;
    }

    float kb[4], vb[4];
#pragma unroll
    for (int c = 0; c < 4; ++c) { kb[c] = keyB[16 * c + l15]; vb[c] = valB[16 * c + l15]; }
    const float sc = scale_p[0];

    // ---- A-fragments (kv) for both row-tiles ----
    f16x8 ah[2][2];
#pragma unroll
    for (int rt = 0; rt < 2; ++rt)
#pragma unroll
        for (int ks = 0; ks < 2; ++ks)
            ah[rt][ks] = *(const f16x8*)&Rly[RB + 16 * rt + l15][ks * 32 + quad * 8];

    // ---- T stage (2rt, T weights loaded once): q = sum_p q'_p*(KV @ T_p^T) ----
    f32x4 qacc[2][4] = {};
#pragma unroll 2
    for (int p = 0; p < 8; ++p) {
        f32x4 tmp[2][4] = {};
        gemm2rt<4>(wsf + OFF_T + p * 4096, l15, quad, ah, tmp);
        f32x4 qp0 = *(const f32x4*)&Qs[p][RB + quad * 4];
        f32x4 qp1 = *(const f32x4*)&Qs[p][RB + 16 + quad * 4];
#pragma unroll
        for (int c = 0; c < 4; ++c)
#pragma unroll
            for (int e = 0; e < 4; ++e) {
                qacc[0][c][e] = fmaf(qp0[e], tmp[0][c][e], qacc[0][c][e]);
                qacc[1][c][e] = fmaf(qp1[e], tmp[1][c][e], qacc[1][c][e]);
            }
    }

    // ---- per row-tile: combined k|v GEMM + elementwise + x relay ----
#pragma unroll 1
    for (int rt = 0; rt < 2; ++rt) {
        f32x4 kv8[8] = {};
        gemm1rt<8>(wsf + OFF_KEY, l15, quad, ah[rt], kv8);

        f32x4 sv[4], mx;
#pragma unroll
        for (int e = 0; e < 4; ++e) mx[e] = -3.4e38f;
#pragma unroll
        for (int c = 0; c < 4; ++c) {
            sv[c] = (kv8[4 + c] + vb[c]) * sc;
#pragma unroll
            for (int e = 0; e < 4; ++e) mx[e] = fmaxf(mx[e], sv[c][e]);
        }
#pragma unroll
        for (int m = 1; m < 16; m <<= 1)
#pragma unroll
            for (int e = 0; e < 4; ++e) mx[e] = fmaxf(mx[e], __shfl_xor(mx[e], m, 64));
        f32x4 se = {};
#pragma unroll
        for (int c = 0; c < 4; ++c) {
#pragma unroll
            for (int e = 0; e < 4; ++e) sv[c][e] = __expf(sv[c][e] - mx[e]);
            se += sv[c];
        }
#pragma unroll
        for (int m = 1; m < 16; m <<= 1)
#pragma unroll
            for (int e = 0; e < 4; ++e) se[e] += __shfl_xor(se[e], m, 64);
        f32x4 nr = {};
        f32x4 at[4];
#pragma unroll
        for (int c = 0; c < 4; ++c) {
            at[c] = qacc[rt][c] * (kv8[c] + kb[c]);
            nr += at[c] * at[c];
        }
#pragma unroll
        for (int m = 1; m < 16; m <<= 1)
#pragma unroll
            for (int e = 0; e < 4; ++e) nr[e] += __shfl_xor(nr[e], m, 64);
        f32x4 fac;
#pragma unroll
        for (int e = 0; e < 4; ++e)
            fac[e] = 1.0f / (fmaxf(sqrtf(nr[e]), 1e-8f) * se[e]);
#pragma unroll
        for (int c = 0; c < 4; ++c)
#pragma unroll
            for (int e = 0; e < 4; ++e)
                Rly[RB + 16 * rt + quad * 4 + e][16 * c + l15] =
                    (f16_t)(at[c][e] * sv[c][e] * fac[e]);
    }

    // ---- d1: h1 = relu(x @ d1 + b1) ----
    f16x8 xh[2][2];
#pragma unroll
    for (int rt = 0; rt < 2; ++rt)
#pragma unroll
        for (int ks = 0; ks < 2; ++ks)
            xh[rt][ks] = *(const f16x8*)&Rly[RB + 16 * rt + l15][ks * 32 + quad * 8];
    f32x4 h1a[2][4] = {};
    gemm2rt<4>(wsf + OFF_D1, l15, quad, xh, h1a);
    {
        float b1[4];
#pragma unroll
        for (int c = 0; c < 4; ++c) b1[c] = d1B[16 * c + l15];
#pragma unroll
        for (int rt = 0; rt < 2; ++rt)
#pragma unroll
            for (int c = 0; c < 4; ++c)
#pragma unroll
                for (int e = 0; e < 4; ++e)
                    Rly[RB + 16 * rt + quad * 4 + e][16 * c + l15] =
                        (f16_t)fmaxf(h1a[rt][c][e] + b1[c], 0.f);
    }

    // ---- d2: h2 = relu(h1 @ d2 + b2), 32 cols ----
#pragma unroll
    for (int rt = 0; rt < 2; ++rt)
#pragma unroll
        for (int ks = 0; ks < 2; ++ks)
            xh[rt][ks] = *(const f16x8*)&Rly[RB + 16 * rt + l15][ks * 32 + quad * 8];
    f32x4 h2a[2][2] = {};
    gemm2rt<2>(wsf + OFF_D2, l15, quad, xh, h2a);
    {
        float b2[2];
#pragma unroll
        for (int c = 0; c < 2; ++c) b2[c] = d2B[16 * c + l15];
#pragma unroll
        for (int rt = 0; rt < 2; ++rt)
#pragma unroll
            for (int c = 0; c < 2; ++c)
#pragma unroll
                for (int e = 0; e < 4; ++e)
                    Rly[RB + 16 * rt + quad * 4 + e][16 * c + l15] =
                        (f16_t)fmaxf(h2a[rt][c][e] + b2[c], 0.f);
    }

    // ---- d3: out = h2 @ d3 + b3 (K=32), epilogue via LDS re-layout ----
    f16x8 a3[2];
#pragma unroll
    for (int rt = 0; rt < 2; ++rt)
        a3[rt] = *(const f16x8*)&Rly[RB + 16 * rt + l15][quad * 8];
    float b3[4];
#pragma unroll
    for (int c = 0; c < 4; ++c) b3[c] = d3B[16 * c + l15];

    const int orow = lane >> 2;          // 0..15
    const int oseg = lane & 3;           // 0..3 (16-float segment)
#pragma unroll
    for (int rt = 0; rt < 2; ++rt) {
#pragma unroll
        for (int c = 0; c < 4; ++c) {
            f16x8 bw = *(const f16x8*)(wsf + OFF_D3 + (16 * c + l15) * 32 + quad * 8);
            f32x4 a = {};
            a = mfma1(a3[rt], bw, a);
#pragma unroll
            for (int e = 0; e < 4; ++e)
                Obuf[wv][quad * 4 + e][16 * c + l15] = a[e] + b3[c];
        }
        // re-read row-major, store lane-contiguous float4 (1 KB per wave-store)
        float* op = out + (t0 + RB + 16 * rt + orow) * 64 + oseg * 16;
#pragma unroll
        for (int k = 0; k < 4; ++k) {
            f32x4 v = *(const f32x4*)&Obuf[wv][orow][oseg * 16 + 4 * k];
            *(f32x4*)(op + 4 * k) = v;
        }
    }
}

extern "C" void kernel_launch(void* const* d_in, const int* in_sizes, int n_in,
                              void* d_out, int out_size, void* d_ws, size_t ws_size,
                              hipStream_t stream) {
    (void)in_sizes; (void)n_in; (void)out_size; (void)ws_size;
    const float* kv_in = (const float*)d_in[0];
    const float* q_in  = (const float*)d_in[1];
    const float* keyW  = (const float*)d_in[2];
    const float* keyB  = (const float*)d_in[3];
    const float* valW  = (const float*)d_in[4];
    const float* valB  = (const float*)d_in[5];
    const float* TW    = (const float*)d_in[6];
    const float* TB    = (const float*)d_in[7];
    const float* d1W   = (const float*)d_in[8];
    const float* d1B   = (const float*)d_in[9];
    const float* d2W   = (const float*)d_in[10];
    const float* d2B   = (const float*)d_in[11];
    const float* d3W   = (const float*)d_in[12];
    const float* d3B   = (const float*)d_in[13];
    const float* scale = (const float*)d_in[14];
    f16_t* wsf = (f16_t*)d_ws;
    float* outp = (float*)d_out;

    prep_w<<<(WTOT + 255) / 256, 256, 0, stream>>>(keyW, valW, TW, TB, d1W, d2W, d3W, wsf);
    fused_mfma<<<NTOK / MT, TPB, 0, stream>>>(kv_in, q_in, keyB, valB,
                                              d1B, d2B, d3B, scale, wsf, outp);
}

// Round 7
// 168.537 us; speedup vs baseline: 1.1110x; 1.1110x over previous
//
#include <hip/hip_runtime.h>
#include <math.h>

typedef _Float16 f16_t;
typedef __attribute__((ext_vector_type(8))) _Float16 f16x8;
typedef __attribute__((ext_vector_type(4))) float f32x4;

#define NTOK 131072
#define MT   256      // tokens per block
#define TPB  512      // 8 waves; 512 blocks = 1 block/CU; ONE barrier total
#define RPAD 76

// ws layout (f16 elems) — unpadded, produced by prep_w
#define OFF_KEY 0
#define OFF_VAL 4096
#define OFF_T   8192
#define OFF_D1  40960
#define OFF_D2  45056
#define OFF_D3  47104
#define WTOT    49152

// LDS weight layout (halfword offsets), stride-76 rows (dword-stride 38 == 6 mod 32
// -> <=2-way bank aliasing on B-frag reads = free); D3 stride 36.
#define LW_KV 0          // 128 rows x 76
#define LW_T  9728       // 512 rows x 76 (8 matrices of 64 rows)
#define LW_D1 48640      // 64 x 76
#define LW_D2 53504      // 32 x 76
#define LW_D3 55936      // 64 x 36
#define LW_TOT 58240     // 116480 B

__device__ __forceinline__ f32x4 mfma1(f16x8 a, f16x8 b, f32x4 c) {
    return __builtin_amdgcn_mfma_f32_16x16x32_f16(a, b, c, 0, 0, 0);
}

// K=64 GEMM from LDS, single row-tile
template<int NC>
__device__ __forceinline__ void gemm1rt(const f16_t* bw, int l15, int quad,
                                        const f16x8 ah[2], f32x4 acc[NC])
{
#pragma unroll
    for (int c = 0; c < NC; ++c) {
        const f16_t* p = bw + (16 * c + l15) * 76 + quad * 8;
        f16x8 b0 = *(const f16x8*)p;
        f16x8 b1 = *(const f16x8*)(p + 32);
        acc[c] = mfma1(ah[1], b1, mfma1(ah[0], b0, acc[c]));
    }
}
// K=64 GEMM from LDS, B shared across both row-tiles
template<int NC>
__device__ __forceinline__ void gemm2rt(const f16_t* bw, int l15, int quad,
                                        const f16x8 ah[2][2], f32x4 acc[2][NC])
{
#pragma unroll
    for (int c = 0; c < NC; ++c) {
        const f16_t* p = bw + (16 * c + l15) * 76 + quad * 8;
        f16x8 b0 = *(const f16x8*)p;
        f16x8 b1 = *(const f16x8*)(p + 32);
#pragma unroll
        for (int rt = 0; rt < 2; ++rt)
            acc[rt][c] = mfma1(ah[rt][1], b1, mfma1(ah[rt][0], b0, acc[rt][c]));
    }
}

// ---------------- prep: transpose all weights into ws as fp16 --------------
__global__ __launch_bounds__(256)
void prep_w(const float* __restrict__ keyW, const float* __restrict__ valW,
            const float* __restrict__ TW,   const float* __restrict__ TB,
            const float* __restrict__ d1W,  const float* __restrict__ d2W,
            const float* __restrict__ d3W,  f16_t* __restrict__ wsf)
{
    int idx = blockIdx.x * 256 + threadIdx.x;
    if (idx >= WTOT) return;
    float src;
    if (idx < OFF_VAL) {
        int r = idx - OFF_KEY, n = r >> 6, j = r & 63;
        src = keyW[j * 64 + n];
    } else if (idx < OFF_T) {
        int r = idx - OFF_VAL, n = r >> 6, j = r & 63;
        src = valW[j * 64 + n];
    } else if (idx < OFF_D1) {
        int r = idx - OFF_T, p = r >> 12, q = r & 4095;
        src = (p < 7) ? TW[p * 4096 + q] : TB[q];
    } else if (idx < OFF_D2) {
        int r = idx - OFF_D1, n = r >> 6, j = r & 63;
        src = d1W[j * 64 + n];
    } else if (idx < OFF_D3) {
        int r = idx - OFF_D2, n = r >> 6, j = r & 63;
        src = d2W[j * 32 + n];
    } else {
        int r = idx - OFF_D3, n = r >> 5, j = r & 31;
        src = d3W[j * 64 + n];
    }
    wsf[idx] = (f16_t)src;
}

// ---------------- main fused kernel: 1 block/CU, weights in LDS ------------
__global__ __launch_bounds__(TPB, 2)
void fused_mfma(const float* __restrict__ kv_in, const float* __restrict__ q_in,
                const float* __restrict__ keyB,  const float* __restrict__ valB,
                const float* __restrict__ d1B,   const float* __restrict__ d2B,
                const float* __restrict__ d3B,   const float* __restrict__ scale_p,
                const f16_t* __restrict__ wsf,   float* __restrict__ out)
{
    __shared__ __align__(16) f16_t WL[LW_TOT];      // 116480 B: all weights, padded
    __shared__ __align__(16) f16_t Rly[MT][RPAD];   // 38912 B: kv staging + relays
    __shared__ __align__(16) float Qs[8][MT];       // 8192 B  -> 163584 B total

    const int tid  = threadIdx.x;
    const int wv   = tid >> 6, lane = tid & 63;
    const int quad = lane >> 4, l15 = lane & 15;
    const int RB   = wv * 32;
    const long t0  = (long)blockIdx.x * MT;

    // ---- cooperative weight staging: ws (unpadded) -> WL (padded) ----
#pragma unroll
    for (int i = 0; i < 12; ++i) {
        int g = i * 4096 + tid * 8;
        f16x8 v = *(const f16x8*)(wsf + g);
        int dst;
        if (g < 8192)       { dst = LW_KV + (g >> 6) * 76 + (g & 63); }
        else if (g < 40960) { int t = g - 8192;  dst = LW_T  + (t >> 6) * 76 + (t & 63); }
        else if (g < 45056) { int t = g - 40960; dst = LW_D1 + (t >> 6) * 76 + (t & 63); }
        else if (g < 47104) { int t = g - 45056; dst = LW_D2 + (t >> 6) * 76 + (t & 63); }
        else                { int t = g - 47104; dst = LW_D3 + (t >> 5) * 36 + (t & 31); }
        *(f16x8*)&WL[dst] = v;
    }

    // ---- coalesced kv staging -> fp16 in LDS (wave-private rows) ----
    {
        const int r = RB + (lane >> 1), half = lane & 1;
        const float4* p4 = (const float4*)(kv_in + (t0 + r) * 64 + half * 32);
        f16_t* dst = &Rly[r][half * 32];
#pragma unroll
        for (int b = 0; b < 4; ++b) {
            float4 f0 = p4[2 * b], f1 = p4[2 * b + 1];
            f16x8 h;
            h[0] = (f16_t)f0.x; h[1] = (f16_t)f0.y; h[2] = (f16_t)f0.z; h[3] = (f16_t)f0.w;
            h[4] = (f16_t)f1.x; h[5] = (f16_t)f1.y; h[6] = (f16_t)f1.z; h[7] = (f16_t)f1.w;
            *(f16x8*)(dst + 8 * b) = h;
        }
    }
    // ---- q' -> Qs (wave-private cols) ----
    if (lane < 32) {
        const float* qp = q_in + (t0 + RB + lane) * 7;
#pragma unroll
        for (int p = 0; p < 7; ++p) Qs[p][RB + lane] = qp[p];
        Qs[7][RB + lane] = 1.0f;
    }

    __syncthreads();   // the ONLY barrier: weights visible to all waves

    float kb[4], vb[4];
#pragma unroll
    for (int c = 0; c < 4; ++c) { kb[c] = keyB[16 * c + l15]; vb[c] = valB[16 * c + l15]; }
    const float sc = scale_p[0];

    // ---- A-fragments (kv) for both row-tiles ----
    f16x8 ah[2][2];
#pragma unroll
    for (int rt = 0; rt < 2; ++rt)
#pragma unroll
        for (int ks = 0; ks < 2; ++ks)
            ah[rt][ks] = *(const f16x8*)&Rly[RB + 16 * rt + l15][ks * 32 + quad * 8];

    // ---- T stage (2rt): q = sum_p q'_p * (KV @ T_p^T) ----
    f32x4 qacc[2][4] = {};
#pragma unroll 2
    for (int p = 0; p < 8; ++p) {
        f32x4 tmp[2][4] = {};
        gemm2rt<4>(&WL[LW_T + p * 4864], l15, quad, ah, tmp);
        f32x4 qp0 = *(const f32x4*)&Qs[p][RB + quad * 4];
        f32x4 qp1 = *(const f32x4*)&Qs[p][RB + 16 + quad * 4];
#pragma unroll
        for (int c = 0; c < 4; ++c)
#pragma unroll
            for (int e = 0; e < 4; ++e) {
                qacc[0][c][e] = fmaf(qp0[e], tmp[0][c][e], qacc[0][c][e]);
                qacc[1][c][e] = fmaf(qp1[e], tmp[1][c][e], qacc[1][c][e]);
            }
    }

    // ---- per row-tile: combined k|v GEMM + elementwise + x relay ----
#pragma unroll 1
    for (int rt = 0; rt < 2; ++rt) {
        f32x4 kv8[8] = {};
        gemm1rt<8>(&WL[LW_KV], l15, quad, ah[rt], kv8);

        f32x4 sv[4], mx;
#pragma unroll
        for (int e = 0; e < 4; ++e) mx[e] = -3.4e38f;
#pragma unroll
        for (int c = 0; c < 4; ++c) {
            sv[c] = (kv8[4 + c] + vb[c]) * sc;
#pragma unroll
            for (int e = 0; e < 4; ++e) mx[e] = fmaxf(mx[e], sv[c][e]);
        }
#pragma unroll
        for (int m = 1; m < 16; m <<= 1)
#pragma unroll
            for (int e = 0; e < 4; ++e) mx[e] = fmaxf(mx[e], __shfl_xor(mx[e], m, 64));
        f32x4 se = {};
#pragma unroll
        for (int c = 0; c < 4; ++c) {
#pragma unroll
            for (int e = 0; e < 4; ++e) sv[c][e] = __expf(sv[c][e] - mx[e]);
            se += sv[c];
        }
#pragma unroll
        for (int m = 1; m < 16; m <<= 1)
#pragma unroll
            for (int e = 0; e < 4; ++e) se[e] += __shfl_xor(se[e], m, 64);
        f32x4 nr = {};
        f32x4 at[4];
#pragma unroll
        for (int c = 0; c < 4; ++c) {
            at[c] = qacc[rt][c] * (kv8[c] + kb[c]);
            nr += at[c] * at[c];
        }
#pragma unroll
        for (int m = 1; m < 16; m <<= 1)
#pragma unroll
            for (int e = 0; e < 4; ++e) nr[e] += __shfl_xor(nr[e], m, 64);
        f32x4 fac;
#pragma unroll
        for (int e = 0; e < 4; ++e)
            fac[e] = 1.0f / (fmaxf(sqrtf(nr[e]), 1e-8f) * se[e]);
#pragma unroll
        for (int c = 0; c < 4; ++c)
#pragma unroll
            for (int e = 0; e < 4; ++e)
                Rly[RB + 16 * rt + quad * 4 + e][16 * c + l15] =
                    (f16_t)(at[c][e] * sv[c][e] * fac[e]);
    }

    // ---- d1: h1 = relu(x @ d1 + b1) ----
    f16x8 xh[2][2];
#pragma unroll
    for (int rt = 0; rt < 2; ++rt)
#pragma unroll
        for (int ks = 0; ks < 2; ++ks)
            xh[rt][ks] = *(const f16x8*)&Rly[RB + 16 * rt + l15][ks * 32 + quad * 8];
    f32x4 h1a[2][4] = {};
    gemm2rt<4>(&WL[LW_D1], l15, quad, xh, h1a);
    {
        float b1[4];
#pragma unroll
        for (int c = 0; c < 4; ++c) b1[c] = d1B[16 * c + l15];
#pragma unroll
        for (int rt = 0; rt < 2; ++rt)
#pragma unroll
            for (int c = 0; c < 4; ++c)
#pragma unroll
                for (int e = 0; e < 4; ++e)
                    Rly[RB + 16 * rt + quad * 4 + e][16 * c + l15] =
                        (f16_t)fmaxf(h1a[rt][c][e] + b1[c], 0.f);
    }

    // ---- d2: h2 = relu(h1 @ d2 + b2), 32 cols ----
#pragma unroll
    for (int rt = 0; rt < 2; ++rt)
#pragma unroll
        for (int ks = 0; ks < 2; ++ks)
            xh[rt][ks] = *(const f16x8*)&Rly[RB + 16 * rt + l15][ks * 32 + quad * 8];
    f32x4 h2a[2][2] = {};
    gemm2rt<2>(&WL[LW_D2], l15, quad, xh, h2a);
    {
        float b2[2];
#pragma unroll
        for (int c = 0; c < 2; ++c) b2[c] = d2B[16 * c + l15];
#pragma unroll
        for (int rt = 0; rt < 2; ++rt)
#pragma unroll
            for (int c = 0; c < 2; ++c)
#pragma unroll
                for (int e = 0; e < 4; ++e)
                    Rly[RB + 16 * rt + quad * 4 + e][16 * c + l15] =
                        (f16_t)fmaxf(h2a[rt][c][e] + b2[c], 0.f);
    }

    // ---- d3: out = h2 @ d3 + b3 (K=32) ----
    f16x8 a3[2];
#pragma unroll
    for (int rt = 0; rt < 2; ++rt)
        a3[rt] = *(const f16x8*)&Rly[RB + 16 * rt + l15][quad * 8];
    float b3[4];
#pragma unroll
    for (int c = 0; c < 4; ++c) b3[c] = d3B[16 * c + l15];
#pragma unroll
    for (int c = 0; c < 4; ++c) {
        f16x8 bw = *(const f16x8*)&WL[LW_D3 + (16 * c + l15) * 36 + quad * 8];
#pragma unroll
        for (int rt = 0; rt < 2; ++rt) {
            f32x4 a = {};
            a = mfma1(a3[rt], bw, a);
            float* op = out + (t0 + RB + 16 * rt + quad * 4) * 64 + 16 * c + l15;
#pragma unroll
            for (int e = 0; e < 4; ++e) op[e * 64] = a[e] + b3[c];
        }
    }
}

extern "C" void kernel_launch(void* const* d_in, const int* in_sizes, int n_in,
                              void* d_out, int out_size, void* d_ws, size_t ws_size,
                              hipStream_t stream) {
    (void)in_sizes; (void)n_in; (void)out_size; (void)ws_size;
    const float* kv_in = (const float*)d_in[0];
    const float* q_in  = (const float*)d_in[1];
    const float* keyW  = (const float*)d_in[2];
    const float* keyB  = (const float*)d_in[3];
    const float* valW  = (const float*)d_in[4];
    const float* valB  = (const float*)d_in[5];
    const float* TW    = (const float*)d_in[6];
    const float* TB    = (const float*)d_in[7];
    const float* d1W   = (const float*)d_in[8];
    const float* d1B   = (const float*)d_in[9];
    const float* d2W   = (const float*)d_in[10];
    const float* d2B   = (const float*)d_in[11];
    const float* d3W   = (const float*)d_in[12];
    const float* d3B   = (const float*)d_in[13];
    const float* scale = (const float*)d_in[14];
    f16_t* wsf = (f16_t*)d_ws;
    float* outp = (float*)d_out;

    prep_w<<<(WTOT + 255) / 256, 256, 0, stream>>>(keyW, valW, TW, TB, d1W, d2W, d3W, wsf);
    fused_mfma<<<NTOK / MT, TPB, 0, stream>>>(kv_in, q_in, keyB, valB,
                                              d1B, d2B, d3B, scale, wsf, outp);
}